// Round 6
// baseline (289.809 us; speedup 1.0000x reference)
//
#include <hip/hip_runtime.h>

// CenterNeighAtt on MI355X. E=512, F=256, R=4.
//
// Exact math simplifications (validated R1-R5, absmax ~5e-4 vs 2.3e-3 threshold):
//  * alpha = softmax_j(sum_i scores[i,j]) is uniform 1/E: sum_i attention[i,j,f]==1,
//    so column sums of scores are constant in j. lin_w/lin_b are dead inputs.
//  * No max-subtraction in softmaxes: logits bounded (~20), exp far below f32 overflow.
//
// R6: 2 dispatches. R5 post-mortem: register "staging" arrays were runtime-indexed
// under partial unroll -> scratch (VGPR=64, VALUBusy 15%, kC=78us). R4's 44.8us was
// ~23us work + ~15us of inter-dispatch gaps (~5us each, R2/R4 cross-check).
//  K1 (512 blk): s row-softmax; zero Z/Hp/cnt/bar; alpha.   (kernel boundary = barrier 1)
//  K2 (1024 blk, all co-resident: launch_bounds(256,4) => VGPR<=128 => 4 blk/CU):
//    P2: Z[j,f] += sum_{i chunk} exp2(lrelu(s*h_if*h_jf)*log2e)   [TT=4 j/blk, 1M atomics]
//    -- hand-rolled L2 flag barrier (NOT coop grid.sync: R3 measured ~55us/sync) --
//    P3: Hp[i,f] += sum_{j chunk} (h_jf*rcp(Z))*exp2(...); last-of-8 finisher ELUs.
// All per-thread arrays TT=4, statically indexed (full unroll) - no scratch.

#define EE 512
#define FF 256
#define RRR 4
#define LOG2E 1.44269504088896340736f
#define TT 4            // rows per block (P2: j's, P3: i's)
#define NCH 8           // reduction-axis chunks
#define CLEN 64         // 512 / NCH
#define NGRP (EE / TT)  // 128 row-groups
#define NBLK2 (NGRP * NCH)  // 1024

// --- K1: s[i,:] = softmax_j(sum_r adj[r,i,:]); zero Z/Hp/ints; alpha -------
__global__ __launch_bounds__(256) void k1(const float* __restrict__ adj,
                                          float* __restrict__ s,
                                          float* __restrict__ Z,
                                          float* __restrict__ Hp,
                                          int* __restrict__ ints,
                                          float* __restrict__ out) {
    const int i = blockIdx.x;
    const int t = threadIdx.x;
    Z[i * 256 + t]  = 0.f;            // E*F floats, covered exactly by grid
    Hp[i * 256 + t] = 0.f;
    if (i == 0) {
        if (t <= NGRP) ints[t] = 0;   // cnt[0..127] + bar (ints[128])
        out[EE * FF + t]       = 1.0f / EE;   // alpha: softmax of constant = uniform
        out[EE * FF + 256 + t] = 1.0f / EE;
    }
    const float* base = adj + (size_t)i * EE;
    float t0 = 0.f, t1 = 0.f;
#pragma unroll
    for (int r = 0; r < RRR; ++r) {
        t0 += base[(size_t)r * EE * EE + t];
        t1 += base[(size_t)r * EE * EE + t + 256];
    }
    const float e0 = __expf(t0);
    const float e1 = __expf(t1);
    __shared__ float red[256];
    red[t] = e0 + e1;
    __syncthreads();
    for (int off = 128; off > 0; off >>= 1) {
        if (t < off) red[t] += red[t + off];
        __syncthreads();
    }
    const float inv = 1.0f / red[0];
    s[(size_t)i * EE + t]       = e0 * inv;
    s[(size_t)i * EE + t + 256] = e1 * inv;
}

// --- K2: P2 (Z atomics) -> flag barrier -> P3 (Hp atomics + ELU finisher) --
__global__ __launch_bounds__(256, 4) void k2(const float* __restrict__ h,
                                             const float* __restrict__ s,
                                             float* __restrict__ Z,
                                             float* __restrict__ Hp,
                                             int* __restrict__ ints,
                                             float* __restrict__ out) {
    const int b   = blockIdx.x;
    const int f   = threadIdx.x;
    const int grp = b >> 3;   // 0..127 (row group)
    const int ch  = b & 7;    // 0..7   (reduction chunk)
    __shared__ float4 sl4[CLEN];                   // P2 s-tile: [ii] -> 4 j's
    __shared__ __align__(16) float slf[CLEN * TT]; // P3 s-tile: [jj][ti]

    // ---------------- P2: partial denominators ----------------------------
    {
        const int j0 = grp * TT;
        const int i0 = ch * CLEN;
        if (f < CLEN)   // one float4 per s-row: s[i0+f][j0..j0+3] (j0 mult of 4 -> aligned)
            sl4[f] = *(const float4*)(s + (size_t)(i0 + f) * EE + j0);
        __syncthreads();
        float hj[TT], Zl[TT];
#pragma unroll
        for (int tj = 0; tj < TT; ++tj) {
            hj[tj] = h[(size_t)(j0 + tj) * FF + f] * LOG2E;   // fold log2e
            Zl[tj] = 0.f;
        }
#pragma unroll 4
        for (int ii = 0; ii < CLEN; ++ii) {
            const float hif = h[(size_t)(i0 + ii) * FF + f];
            const float4 sa = sl4[ii];                        // b128 broadcast
            const float sv[TT] = {sa.x, sa.y, sa.z, sa.w};
#pragma unroll
            for (int tj = 0; tj < TT; ++tj) {
                const float y = sv[tj] * hif * hj[tj];
                Zl[tj] += __builtin_amdgcn_exp2f(fmaxf(y, 0.2f * y));  // lrelu folded
            }
        }
#pragma unroll
        for (int tj = 0; tj < TT; ++tj)
            atomicAdd(&Z[(size_t)(j0 + tj) * FF + f], Zl[tj]);
    }

    // ---------------- global flag barrier (bar = ints[NGRP], zeroed by K1) -
    __syncthreads();
    if (f == 0) {
        __threadfence();                      // release: my Z adds complete+visible
        atomicAdd(&ints[NGRP], 1);
        while (__hip_atomic_load(&ints[NGRP], __ATOMIC_RELAXED,
                                 __HIP_MEMORY_SCOPE_AGENT) < NBLK2)
            __builtin_amdgcn_s_sleep(8);
    }
    __syncthreads();
    __threadfence();                          // acquire: invalidate L1, Z reads fresh

    // ---------------- P3: numerators + finisher ----------------------------
    {
        const int i0 = grp * TT;
        const int j0 = ch * CLEN;
        // slf[jj*4+ti] = s[i0+ti][j0+jj]; store addr == f (linear, conflict-free)
        slf[f] = s[(size_t)(i0 + (f & 3)) * EE + j0 + (f >> 2)];
        __syncthreads();
        float hl[TT], acc[TT];
#pragma unroll
        for (int ti = 0; ti < TT; ++ti) {
            hl[ti] = h[(size_t)(i0 + ti) * FF + f] * LOG2E;
            acc[ti] = 0.f;
        }
#pragma unroll 4
        for (int jj = 0; jj < CLEN; ++jj) {
            const float hjf = h[(size_t)(j0 + jj) * FF + f];
            const float gj  = hjf * __builtin_amdgcn_rcpf(Z[(size_t)(j0 + jj) * FF + f]);
            const float4 sa = ((const float4*)slf)[jj];       // b128 broadcast
            const float sv[TT] = {sa.x, sa.y, sa.z, sa.w};
#pragma unroll
            for (int ti = 0; ti < TT; ++ti) {
                const float y = sv[ti] * hl[ti] * hjf;
                acc[ti] = fmaf(__builtin_amdgcn_exp2f(fmaxf(y, 0.2f * y)), gj, acc[ti]);
            }
        }
#pragma unroll
        for (int ti = 0; ti < TT; ++ti)
            atomicAdd(&Hp[(size_t)(i0 + ti) * FF + f], acc[ti]);

        // last-of-8 finisher for this row group applies ELU
        __threadfence();                      // release: my Hp adds complete
        __syncthreads();
        __shared__ int sdone;
        if (f == 0) sdone = (atomicAdd(&ints[grp], 1) == NCH - 1) ? 1 : 0;
        __syncthreads();
        if (sdone) {
            __threadfence();                  // acquire: others' Hp adds visible
#pragma unroll
            for (int ti = 0; ti < TT; ++ti) {
                const float a = Hp[(size_t)(i0 + ti) * FF + f];
                out[(size_t)(i0 + ti) * FF + f] = (a > 0.f) ? a : (__expf(a) - 1.0f);
            }
        }
    }
}

extern "C" void kernel_launch(void* const* d_in, const int* in_sizes, int n_in,
                              void* d_out, int out_size, void* d_ws, size_t ws_size,
                              hipStream_t stream) {
    const float* h   = (const float*)d_in[0];  // [E,F]
    const float* adj = (const float*)d_in[1];  // [R,E,E]
    // lin_w / lin_b mathematically dead (alpha uniform).

    float* s   = (float*)d_ws;                  // 1 MB
    float* Z   = s + (size_t)EE * EE;           // 512 KB
    float* Hp  = Z + (size_t)EE * FF;           // 512 KB
    int*  ints = (int*)(Hp + (size_t)EE * FF);  // 129 ints (cnt[128] + bar)
    float* out = (float*)d_out;

    k1<<<EE, 256, 0, stream>>>(adj, s, Z, Hp, ints, out);
    k2<<<NBLK2, 256, 0, stream>>>(h, s, Z, Hp, ints, out);
}

// Round 7
// 102.210 us; speedup vs baseline: 2.8354x; 2.8354x over previous
//
#include <hip/hip_runtime.h>

// CenterNeighAtt on MI355X. E=512, F=256, R=4.
//
// Exact math simplifications (validated R1-R6, absmax ~5e-4 vs 2.3e-3 threshold):
//  * alpha = softmax_j(sum_i scores[i,j]) is uniform 1/E: sum_i attention[i,j,f]==1,
//    so column sums of scores are constant in j. lin_w/lin_b are dead inputs.
//  * No max-subtraction in softmaxes: logits bounded (~20), exp far below f32 overflow.
//
// Structure lessons (measured):
//  * R3 coop grid.sync ~55us each; R6 hand-rolled flag barrier ~270us. Cross-grid
//    sync inside one dispatch is toxic on 8 non-coherent XCDs -> kernel boundaries only.
//  * Real VALU work is ~23-24us total (confirmed 3x: R3/R5/R6 VALUBusy x dur).
//  * R5: CLEN-sized per-thread arrays under partial unroll -> scratch (rule #20). Only
//    TT-sized, fully-unrolled arrays allowed.
// R7 = R4 (best, 44.8us) + NCH 8->16 (4 blocks/CU TLP) + kC2 folded into kC finisher.

#define EE 512
#define FF 256
#define RRR 4
#define LOG2E 1.44269504088896340736f
#define TT 8            // rows per block (kB: j's, kC: i's)
#define NCH 16          // reduction-axis chunks
#define CLEN 32         // 512 / NCH
#define NGRP (EE / TT)  // 64 row-groups

// --- kA: zero Z/Hp/cnt; s[i,:] = softmax_j(sum_r adj[r,i,:]); alpha --------
__global__ __launch_bounds__(256) void kA(const float* __restrict__ adj,
                                          float* __restrict__ s,
                                          float* __restrict__ Z,
                                          float* __restrict__ Hp,
                                          int* __restrict__ cnt,
                                          float* __restrict__ out) {
    const int i = blockIdx.x;
    const int t = threadIdx.x;
    Z[i * 256 + t]  = 0.f;            // E*F floats, covered exactly by grid
    Hp[i * 256 + t] = 0.f;
    if (i == 0) {
        if (t < NGRP) cnt[t] = 0;     // kC finisher counters
        out[EE * FF + t]       = 1.0f / EE;   // alpha: softmax of constant = uniform
        out[EE * FF + 256 + t] = 1.0f / EE;
    }
    const float* base = adj + (size_t)i * EE;
    float t0 = 0.f, t1 = 0.f;
#pragma unroll
    for (int r = 0; r < RRR; ++r) {
        t0 += base[(size_t)r * EE * EE + t];
        t1 += base[(size_t)r * EE * EE + t + 256];
    }
    const float e0 = __expf(t0);
    const float e1 = __expf(t1);
    __shared__ float red[256];
    red[t] = e0 + e1;
    __syncthreads();
    for (int off = 128; off > 0; off >>= 1) {
        if (t < off) red[t] += red[t + off];
        __syncthreads();
    }
    const float inv = 1.0f / red[0];
    s[(size_t)i * EE + t]       = e0 * inv;
    s[(size_t)i * EE + t + 256] = e1 * inv;
}

// --- kB: Z[j,f] += sum_{i in chunk} exp2(lrelu(s*h_if*h_jf)*log2e) ---------
__global__ __launch_bounds__(256) void kB(const float* __restrict__ h,
                                          const float* __restrict__ s,
                                          float* __restrict__ Z) {
    const int j0 = blockIdx.x * TT;    // 64 j-groups
    const int i0 = blockIdx.y * CLEN;  // 16 i-chunks
    const int f  = threadIdx.x;
    __shared__ float4 sl4[CLEN * 2];   // s[i0+ii][j0..j0+7] as two float4 per row
    if (f < CLEN * 2)                  // j0 multiple of 8 -> 16B aligned
        sl4[f] = ((const float4*)(s + (size_t)(i0 + (f >> 1)) * EE + j0))[f & 1];
    __syncthreads();
    float hj[TT], Zl[TT];
#pragma unroll
    for (int tj = 0; tj < TT; ++tj) {
        hj[tj] = h[(size_t)(j0 + tj) * FF + f] * LOG2E;  // fold log2e
        Zl[tj] = 0.f;
    }
#pragma unroll 4
    for (int ii = 0; ii < CLEN; ++ii) {
        const float hif = h[(size_t)(i0 + ii) * FF + f];
        const float4 sa = sl4[ii * 2];       // ds_read_b128 broadcast (conflict-free)
        const float4 sb = sl4[ii * 2 + 1];
        const float sv[8] = {sa.x, sa.y, sa.z, sa.w, sb.x, sb.y, sb.z, sb.w};
#pragma unroll
        for (int tj = 0; tj < TT; ++tj) {
            const float y = sv[tj] * hif * hj[tj];
            Zl[tj] += __builtin_amdgcn_exp2f(fmaxf(y, 0.2f * y));  // lrelu folded
        }
    }
#pragma unroll
    for (int tj = 0; tj < TT; ++tj)
        atomicAdd(&Z[(size_t)(j0 + tj) * FF + f], Zl[tj]);
}

// --- kC: Hp[i,f] += sum_{j in chunk} (h_jf*rcp(Z_jf))*exp2(...);
//         16th block per i-group applies ELU and writes out ----------------
__global__ __launch_bounds__(256) void kC(const float* __restrict__ h,
                                          const float* __restrict__ s,
                                          const float* __restrict__ Z,
                                          float* __restrict__ Hp,
                                          int* __restrict__ cnt,
                                          float* __restrict__ out) {
    const int i0 = blockIdx.x * TT;    // 64 i-groups
    const int j0 = blockIdx.y * CLEN;  // 16 j-chunks
    const int f  = threadIdx.x;
    __shared__ __align__(16) float slf[CLEN * TT];   // [jj][ti] transposed s-tile
    {   // coalesced global read: ti = f>>5 (0..7), jj = f&31
        const int ti = f >> 5, jj = f & 31;
        slf[jj * TT + ti] = s[(size_t)(i0 + ti) * EE + j0 + jj];
    }
    __syncthreads();
    float hl[TT], acc[TT];
#pragma unroll
    for (int ti = 0; ti < TT; ++ti) {
        hl[ti] = h[(size_t)(i0 + ti) * FF + f] * LOG2E;
        acc[ti] = 0.f;
    }
#pragma unroll 4
    for (int jj = 0; jj < CLEN; ++jj) {
        const float hjf = h[(size_t)(j0 + jj) * FF + f];
        const float gj  = hjf * __builtin_amdgcn_rcpf(Z[(size_t)(j0 + jj) * FF + f]);
        const float4 sa = ((const float4*)slf)[jj * 2];   // b128 broadcasts
        const float4 sb = ((const float4*)slf)[jj * 2 + 1];
        const float sv[8] = {sa.x, sa.y, sa.z, sa.w, sb.x, sb.y, sb.z, sb.w};
#pragma unroll
        for (int ti = 0; ti < TT; ++ti) {
            const float y = sv[ti] * hl[ti] * hjf;
            acc[ti] = fmaf(__builtin_amdgcn_exp2f(fmaxf(y, 0.2f * y)), gj, acc[ti]);
        }
    }
#pragma unroll
    for (int ti = 0; ti < TT; ++ti)
        atomicAdd(&Hp[(size_t)(i0 + ti) * FF + f], acc[ti]);

    // split-K finisher: the 16th block for this i-group applies ELU.
    __threadfence();                   // release: my Hp adds visible before counter
    __syncthreads();
    __shared__ int sdone;
    if (f == 0) sdone = (atomicAdd(&cnt[blockIdx.x], 1) == NCH - 1) ? 1 : 0;
    __syncthreads();
    if (sdone) {
        __threadfence();               // acquire: other blocks' adds visible
#pragma unroll
        for (int ti = 0; ti < TT; ++ti) {
            const float a = Hp[(size_t)(i0 + ti) * FF + f];
            out[(size_t)(i0 + ti) * FF + f] = (a > 0.f) ? a : (__expf(a) - 1.0f);
        }
    }
}

extern "C" void kernel_launch(void* const* d_in, const int* in_sizes, int n_in,
                              void* d_out, int out_size, void* d_ws, size_t ws_size,
                              hipStream_t stream) {
    const float* h   = (const float*)d_in[0];  // [E,F]
    const float* adj = (const float*)d_in[1];  // [R,E,E]
    // lin_w / lin_b mathematically dead (alpha uniform).

    float* s   = (float*)d_ws;                  // 1 MB
    float* Z   = s + (size_t)EE * EE;           // 512 KB
    float* Hp  = Z + (size_t)EE * FF;           // 512 KB
    int*  cnt  = (int*)(Hp + (size_t)EE * FF);  // 64 ints
    float* out = (float*)d_out;

    kA<<<EE, 256, 0, stream>>>(adj, s, Z, Hp, cnt, out);
    kB<<<dim3(EE / TT, NCH), 256, 0, stream>>>(h, s, Z);
    kC<<<dim3(EE / TT, NCH), 256, 0, stream>>>(h, s, Z, Hp, cnt, out);
}

// Round 8
// 43.599 us; speedup vs baseline: 6.6472x; 2.3443x over previous
//
#include <hip/hip_runtime.h>

// CenterNeighAtt on MI355X. E=512, F=256, R=4.
//
// Exact math simplifications (validated R1-R7, absmax ~5e-4 vs 2.3e-3 threshold):
//  * alpha = softmax_j(sum_i scores[i,j]) is uniform 1/E: sum_i attention[i,j,f]==1,
//    so column sums of scores are constant in j. lin_w/lin_b are dead inputs.
//  * No max-subtraction in softmaxes: logits bounded (~20), exp far below f32 overflow.
//
// Structure lessons (measured):
//  * Cross-grid sync in-dispatch is toxic: coop grid.sync ~55us (R3), flag barrier
//    ~270us (R6). __threadfence() per block is toxic on 8 non-coherent XCDs:
//    R5/R7 finisher kernels 78-85us at ~13% VALUBusy. Kernel boundaries ONLY.
//  * Real VALU work ~23us total (confirmed R3/R5/R6/R7: VALUBusy x dur).
//  * Rule #20: only TT-sized, fully-unrolled per-thread arrays (R5 scratch bug).
//
// R8: in-block split-reduction => no atomics, no fences, no zero-init, 3 dispatches.
//  kA (512 blk x 256):  s[i,:] = softmax_j(sum_r adj[r,i,:]); alpha = 1/E.
//  kB (256 blk x 1024): 2 j's/block, i split across 4 teams, LDS-reduce,
//                       g[j,f] = h[j,f] * rcp(Z[j,f]) written with plain stores.
//  kC (256 blk x 1024): 2 i's/block, j split across 4 teams, LDS-reduce,
//                       out[i,f] = elu(sum_j g*exp2(lrelu(s*h_if*h_jf)*log2e)).

#define EE 512
#define FF 256
#define RRR 4
#define LOG2E 1.44269504088896340736f

// --- kA: s[i,:] = softmax_j(sum_r adj[r,i,:]); alpha -----------------------
__global__ __launch_bounds__(256) void kA(const float* __restrict__ adj,
                                          float* __restrict__ s,
                                          float* __restrict__ out) {
    const int i = blockIdx.x;
    const int t = threadIdx.x;
    if (i == 0) {   // alpha: softmax of a constant vector = uniform 1/E
        out[EE * FF + t]       = 1.0f / EE;
        out[EE * FF + 256 + t] = 1.0f / EE;
    }
    const float* base = adj + (size_t)i * EE;
    float t0 = 0.f, t1 = 0.f;
#pragma unroll
    for (int r = 0; r < RRR; ++r) {
        t0 += base[(size_t)r * EE * EE + t];
        t1 += base[(size_t)r * EE * EE + t + 256];
    }
    const float e0 = __expf(t0);
    const float e1 = __expf(t1);
    __shared__ float red[256];
    red[t] = e0 + e1;
    __syncthreads();
    for (int off = 128; off > 0; off >>= 1) {
        if (t < off) red[t] += red[t + off];
        __syncthreads();
    }
    const float inv = 1.0f / red[0];
    s[(size_t)i * EE + t]       = e0 * inv;
    s[(size_t)i * EE + t + 256] = e1 * inv;
}

// --- kB: g[j,f] = h[j,f] / sum_i exp2(lrelu(s[i,j]*h[i,f]*h[j,f])*log2e) ---
__global__ __launch_bounds__(1024, 4) void kB(const float* __restrict__ h,
                                              const float* __restrict__ s,
                                              float* __restrict__ g) {
    const int tid  = threadIdx.x;
    const int f    = tid & 255;
    const int team = tid >> 8;            // 0..3, splits the i-axis
    const int j0   = blockIdx.x * 2;
    __shared__ float sl[2 * EE];          // sl[jp*512 + i] = s[i][j0+jp]
    __shared__ float ps[8 * FF];          // ps[(p*4+team)*256 + f]
    sl[tid] = s[(size_t)(tid & 511) * EE + j0 + (tid >> 9)];  // 1 scattered 4B load/thread
    __syncthreads();
    const float hj0 = h[(size_t)j0 * FF + f] * LOG2E;         // fold log2e
    const float hj1 = h[(size_t)(j0 + 1) * FF + f] * LOG2E;
    float Z0 = 0.f, Z1 = 0.f;
    const int ib = team * 128;
#pragma unroll 4
    for (int ii = 0; ii < 128; ++ii) {
        const float hif = h[(size_t)(ib + ii) * FF + f];      // coalesced, L2-resident
        const float y0 = sl[ib + ii] * hif * hj0;             // LDS broadcast
        const float y1 = sl[512 + ib + ii] * hif * hj1;
        Z0 += __builtin_amdgcn_exp2f(fmaxf(y0, 0.2f * y0));   // lrelu folded
        Z1 += __builtin_amdgcn_exp2f(fmaxf(y1, 0.2f * y1));
    }
    ps[(0 * 4 + team) * 256 + f] = Z0;
    ps[(1 * 4 + team) * 256 + f] = Z1;
    __syncthreads();
    if (tid < 512) {                       // p = tid>>8, f2 = tid&255
        const int p = tid >> 8, f2 = tid & 255;
        const float Z = ps[p * 1024 + f2]       + ps[p * 1024 + 256 + f2]
                      + ps[p * 1024 + 512 + f2] + ps[p * 1024 + 768 + f2];
        g[(size_t)(j0 + p) * FF + f2] =
            h[(size_t)(j0 + p) * FF + f2] * __builtin_amdgcn_rcpf(Z);
    }
}

// --- kC: out[i,f] = elu(sum_j g[j,f]*exp2(lrelu(s[i,j]*h[i,f]*h[j,f])*log2e))
__global__ __launch_bounds__(1024, 4) void kC(const float* __restrict__ h,
                                              const float* __restrict__ s,
                                              const float* __restrict__ g,
                                              float* __restrict__ out) {
    const int tid  = threadIdx.x;
    const int f    = tid & 255;
    const int team = tid >> 8;            // 0..3, splits the j-axis
    const int i0   = blockIdx.x * 2;
    __shared__ float sl[2 * EE];          // sl[ip*512 + j] = s[i0+ip][j]
    __shared__ float ps[8 * FF];
    sl[tid] = s[(size_t)(i0 + (tid >> 9)) * EE + (tid & 511)];  // coalesced rows
    __syncthreads();
    const float hl0 = h[(size_t)i0 * FF + f] * LOG2E;
    const float hl1 = h[(size_t)(i0 + 1) * FF + f] * LOG2E;
    float a0 = 0.f, a1 = 0.f;
    const int jb = team * 128;
#pragma unroll 4
    for (int jj = 0; jj < 128; ++jj) {
        const int j = jb + jj;
        const float hjf = h[(size_t)j * FF + f];              // coalesced, L2-resident
        const float gj  = g[(size_t)j * FF + f];
        const float y0 = sl[j] * hl0 * hjf;                   // LDS broadcast
        const float y1 = sl[512 + j] * hl1 * hjf;
        a0 = fmaf(__builtin_amdgcn_exp2f(fmaxf(y0, 0.2f * y0)), gj, a0);
        a1 = fmaf(__builtin_amdgcn_exp2f(fmaxf(y1, 0.2f * y1)), gj, a1);
    }
    ps[(0 * 4 + team) * 256 + f] = a0;
    ps[(1 * 4 + team) * 256 + f] = a1;
    __syncthreads();
    if (tid < 512) {
        const int p = tid >> 8, f2 = tid & 255;
        const float a = ps[p * 1024 + f2]       + ps[p * 1024 + 256 + f2]
                      + ps[p * 1024 + 512 + f2] + ps[p * 1024 + 768 + f2];
        out[(size_t)(i0 + p) * FF + f2] = (a > 0.f) ? a : (__expf(a) - 1.0f);
    }
}

extern "C" void kernel_launch(void* const* d_in, const int* in_sizes, int n_in,
                              void* d_out, int out_size, void* d_ws, size_t ws_size,
                              hipStream_t stream) {
    const float* h   = (const float*)d_in[0];  // [E,F]
    const float* adj = (const float*)d_in[1];  // [R,E,E]
    // lin_w / lin_b mathematically dead (alpha uniform).

    float* s   = (float*)d_ws;                 // 1 MB
    float* g   = s + (size_t)EE * EE;          // 512 KB (total 1.5 MB)
    float* out = (float*)d_out;

    kA<<<EE, 256, 0, stream>>>(adj, s, out);
    kB<<<EE / 2, 1024, 0, stream>>>(h, s, g);
    kC<<<EE / 2, 1024, 0, stream>>>(h, s, g, out);
}

// Round 9
// 42.348 us; speedup vs baseline: 6.8435x; 1.0295x over previous
//
#include <hip/hip_runtime.h>

// CenterNeighAtt on MI355X. E=512, F=256, R=4.
//
// Exact math simplifications (validated R1-R8, absmax ~5e-4 vs 2.3e-3 threshold):
//  * alpha = softmax_j(sum_i scores[i,j]) is uniform 1/E: sum_i attention[i,j,f]==1,
//    so column sums of scores are constant in j. lin_w/lin_b are dead inputs.
//  * No max-subtraction in softmaxes: logits bounded (~20), exp far below f32 overflow.
//
// Structure lessons (measured):
//  * Cross-grid sync in-dispatch toxic (coop ~55us/sync R3; flag barrier ~270us R6);
//    __threadfence per block toxic (R5/R7 finishers 78-85us). Kernel boundaries ONLY.
//  * Dispatch gaps are small (~2-4us): R5/R7 calibration kB+3g=15.5.
//  * In-block split-reduction (R8, 256 blk x 1024 thr) is the best structure: 43.6us.
//  * Rule #20: only tiny, fully-unrolled per-thread arrays.
//
// R9 = R8 + packed-f32 inner loops (v_pk_* via float2 ext-vector; CDNA4 fp32 peak
// requires packing), ds_read_b64 s-broadcasts, and kB->kC fused {h,g} float2 loads.

typedef float f2 __attribute__((ext_vector_type(2)));

#define EE 512
#define FF 256
#define RRR 4
#define LOG2E 1.44269504088896340736f

// --- kA: s[i,:] = softmax_j(sum_r adj[r,i,:]); alpha -----------------------
__global__ __launch_bounds__(256) void kA(const float* __restrict__ adj,
                                          float* __restrict__ s,
                                          float* __restrict__ out) {
    const int i = blockIdx.x;
    const int t = threadIdx.x;
    if (i == 0) {   // alpha: softmax of a constant vector = uniform 1/E
        out[EE * FF + t]       = 1.0f / EE;
        out[EE * FF + 256 + t] = 1.0f / EE;
    }
    const float* base = adj + (size_t)i * EE;
    float t0 = 0.f, t1 = 0.f;
#pragma unroll
    for (int r = 0; r < RRR; ++r) {
        t0 += base[(size_t)r * EE * EE + t];
        t1 += base[(size_t)r * EE * EE + t + 256];
    }
    const float e0 = __expf(t0);
    const float e1 = __expf(t1);
    __shared__ float red[256];
    red[t] = e0 + e1;
    __syncthreads();
    for (int off = 128; off > 0; off >>= 1) {
        if (t < off) red[t] += red[t + off];
        __syncthreads();
    }
    const float inv = 1.0f / red[0];
    s[(size_t)i * EE + t]       = e0 * inv;
    s[(size_t)i * EE + t + 256] = e1 * inv;
}

// --- kB: Z[j,f] = sum_i exp2(lrelu(s[i,j]*h[i,f]*h[j,f])*log2e);
//         hg[j,f] = {h[j,f], h[j,f]*rcp(Z)}  (fused operand for kC) ---------
__global__ __launch_bounds__(1024, 4) void kB(const float* __restrict__ h,
                                              const float* __restrict__ s,
                                              f2* __restrict__ hg) {
    const int tid  = threadIdx.x;
    const int f    = tid & 255;
    const int team = tid >> 8;           // 0..3, splits the i-axis
    const int j0   = blockIdx.x * 2;
    __shared__ f2 sl2[EE];               // sl2[i] = {s[i][j0], s[i][j0+1]}
    __shared__ f2 ps[4 * FF];
    // stage: 2 threads per s-row (same cache line), LDS write linear
    ((float*)sl2)[tid] = s[(size_t)(tid >> 1) * EE + j0 + (tid & 1)];
    __syncthreads();
    const f2 hj = {h[(size_t)j0 * FF + f] * LOG2E,
                   h[(size_t)(j0 + 1) * FF + f] * LOG2E};   // log2e folded
    f2 Z = {0.f, 0.f};
    const int ib = team * 128;
#pragma unroll 4
    for (int ii = 0; ii < 128; ++ii) {
        const float hif = h[(size_t)(ib + ii) * FF + f];    // coalesced, L2-resident
        const f2 y = sl2[ib + ii] * hif * hj;               // ds_read_b64 bcast + 2 pk_mul
        const f2 m = __builtin_elementwise_max(y, 0.2f * y);  // pk_mul + pk_max (lrelu)
        const f2 e = {__builtin_amdgcn_exp2f(m.x), __builtin_amdgcn_exp2f(m.y)};
        Z += e;                                             // pk_add
    }
    ps[team * 256 + f] = Z;
    __syncthreads();
    if (tid < 256) {
        const f2 Zt = ps[f] + ps[256 + f] + ps[512 + f] + ps[768 + f];
        const float h0 = h[(size_t)j0 * FF + f];
        const float h1 = h[(size_t)(j0 + 1) * FF + f];
        hg[(size_t)j0 * FF + f]       = (f2){h0, h0 * __builtin_amdgcn_rcpf(Zt.x)};
        hg[(size_t)(j0 + 1) * FF + f] = (f2){h1, h1 * __builtin_amdgcn_rcpf(Zt.y)};
    }
}

// --- kC: out[i,f] = elu(sum_j g[j,f]*exp2(lrelu(s[i,j]*h[i,f]*h[j,f])*log2e))
__global__ __launch_bounds__(1024, 4) void kC(const float* __restrict__ h,
                                              const float* __restrict__ s,
                                              const f2* __restrict__ hg,
                                              float* __restrict__ out) {
    const int tid  = threadIdx.x;
    const int f    = tid & 255;
    const int team = tid >> 8;           // 0..3, splits the j-axis
    const int i0   = blockIdx.x * 2;
    __shared__ f2 sl2[EE];               // sl2[j] = {s[i0][j], s[i0+1][j]}
    __shared__ f2 ps[4 * FF];
    {   // stage: coalesced global rows; LDS stride-2 store (2-way alias = free)
        const int p = tid >> 9, j = tid & 511;
        ((float*)sl2)[j * 2 + p] = s[(size_t)(i0 + p) * EE + j];
    }
    __syncthreads();
    const f2 hl = {h[(size_t)i0 * FF + f] * LOG2E,
                   h[(size_t)(i0 + 1) * FF + f] * LOG2E};
    f2 acc = {0.f, 0.f};
    const int jb = team * 128;
#pragma unroll 4
    for (int jj = 0; jj < 128; ++jj) {
        const f2 hgv = hg[(size_t)(jb + jj) * FF + f];      // one dwordx2: {h_jf, g_jf}
        const f2 y = sl2[jb + jj] * hgv.x * hl;             // b64 bcast + 2 pk_mul
        const f2 m = __builtin_elementwise_max(y, 0.2f * y);
        const f2 e = {__builtin_amdgcn_exp2f(m.x), __builtin_amdgcn_exp2f(m.y)};
        acc += e * hgv.y;                                   // pk_fma
    }
    ps[team * 256 + f] = acc;
    __syncthreads();
    if (tid < 256) {
        const f2 a = ps[f] + ps[256 + f] + ps[512 + f] + ps[768 + f];
        out[(size_t)i0 * FF + f]       = (a.x > 0.f) ? a.x : (__expf(a.x) - 1.0f);
        out[(size_t)(i0 + 1) * FF + f] = (a.y > 0.f) ? a.y : (__expf(a.y) - 1.0f);
    }
}

extern "C" void kernel_launch(void* const* d_in, const int* in_sizes, int n_in,
                              void* d_out, int out_size, void* d_ws, size_t ws_size,
                              hipStream_t stream) {
    const float* h   = (const float*)d_in[0];  // [E,F]
    const float* adj = (const float*)d_in[1];  // [R,E,E]
    // lin_w / lin_b mathematically dead (alpha uniform).

    float* s   = (float*)d_ws;                 // 1 MB
    f2*    hg  = (f2*)(s + (size_t)EE * EE);   // 1 MB {h,g} pairs (total 2 MB)
    float* out = (float*)d_out;

    kA<<<EE, 256, 0, stream>>>(adj, s, out);
    kB<<<EE / 2, 1024, 0, stream>>>(h, s, hg);
    kC<<<EE / 2, 1024, 0, stream>>>(h, s, hg, out);
}